// Round 1
// baseline (578.409 us; speedup 1.0000x reference)
//
#include <hip/hip_runtime.h>

// ---------------- problem constants ----------------
#define BATCH 4
#define SEQ 2048
#define DM 1024
#define NH 16
#define HD 64
#define SCALE 0.125f   // 64^-0.5

typedef unsigned short ushort_t;
typedef short bf16x8 __attribute__((ext_vector_type(8)));
typedef float f32x4 __attribute__((ext_vector_type(4)));

__device__ __forceinline__ ushort_t f2bf(float f) {
    unsigned u = __float_as_uint(f);
    unsigned r = (u + 0x7FFFu + ((u >> 16) & 1u)) >> 16;
    return (ushort_t)r;
}

// ---------------- cast x: f32 -> bf16, 4 elems/thread ----------------
__global__ void cast_f32_bf16(const float* __restrict__ in, ushort_t* __restrict__ out, int n) {
    int i = (blockIdx.x * blockDim.x + threadIdx.x) * 4;
    if (i < n) {
        float4 v = *(const float4*)(in + i);
        ushort4 o;
        o.x = f2bf(v.x); o.y = f2bf(v.y); o.z = f2bf(v.z); o.w = f2bf(v.w);
        *(ushort4*)(out + i) = o;
    }
}

// ---------------- transpose+cast: in[K][N] f32 -> out[N][K] bf16 ----------------
__global__ void transpose_cast(const float* __restrict__ in, ushort_t* __restrict__ out,
                               int K, int N) {
    __shared__ float tile[32][33];
    int n0 = blockIdx.x * 32, k0 = blockIdx.y * 32;
    int x = threadIdx.x, y = threadIdx.y;   // blockDim = (32, 8)
#pragma unroll
    for (int j = 0; j < 32; j += 8)
        tile[y + j][x] = in[(size_t)(k0 + y + j) * N + n0 + x];
    __syncthreads();
#pragma unroll
    for (int j = 0; j < 32; j += 8)
        out[(size_t)(n0 + y + j) * K + k0 + x] = f2bf(tile[x][y + j]);
}

// ---------------- GEMM: C[M][N] = A[M][K] @ Bt[N][K]^T + bias[N] ----------------
// 128x128 tile, 256 threads (4 waves 2x2), BK=32, mfma_f32_16x16x32_bf16.
// A/B frag (verified layout): lane l elem i -> X[l&15][(l>>4)*8+i]
// C/D: lane l reg r -> D[(l>>4)*4+r][l&15]
template <bool OUT_F32>
__global__ __launch_bounds__(256) void gemm_abt(
    const ushort_t* __restrict__ A, const ushort_t* __restrict__ Bt,
    const float* __restrict__ bias, void* __restrict__ Cout,
    int M, int N, int K) {
    __shared__ __attribute__((aligned(16))) ushort_t As[128][40];
    __shared__ __attribute__((aligned(16))) ushort_t Bs[128][40];
    const int tid = threadIdx.x;
    const int lane = tid & 63, wave = tid >> 6;
    const int l15 = lane & 15, l4 = lane >> 4;
    const int m0 = blockIdx.y * 128, n0 = blockIdx.x * 128;
    const int wr = (wave >> 1) * 64, wc = (wave & 1) * 64;

    const int ar = tid >> 1, ac = (tid & 1) * 16;
    const ushort_t* gA = A + (size_t)(m0 + ar) * K + ac;
    const ushort_t* gB = Bt + (size_t)(n0 + ar) * K + ac;

    f32x4 acc[4][4];
#pragma unroll
    for (int i = 0; i < 4; ++i)
#pragma unroll
        for (int j = 0; j < 4; ++j) acc[i][j] = (f32x4){0.f, 0.f, 0.f, 0.f};

    for (int k0 = 0; k0 < K; k0 += 32) {
        __syncthreads();
        *(uint4*)&As[ar][ac]     = *(const uint4*)(gA + k0);
        *(uint4*)&As[ar][ac + 8] = *(const uint4*)(gA + k0 + 8);
        *(uint4*)&Bs[ar][ac]     = *(const uint4*)(gB + k0);
        *(uint4*)&Bs[ar][ac + 8] = *(const uint4*)(gB + k0 + 8);
        __syncthreads();
        bf16x8 a[4], b[4];
#pragma unroll
        for (int i = 0; i < 4; ++i) {
            a[i] = *(const bf16x8*)&As[wr + i * 16 + l15][l4 * 8];
            b[i] = *(const bf16x8*)&Bs[wc + i * 16 + l15][l4 * 8];
        }
#pragma unroll
        for (int mi = 0; mi < 4; ++mi)
#pragma unroll
            for (int ni = 0; ni < 4; ++ni)
                acc[mi][ni] = __builtin_amdgcn_mfma_f32_16x16x32_bf16(
                    a[mi], b[ni], acc[mi][ni], 0, 0, 0);
    }

#pragma unroll
    for (int mi = 0; mi < 4; ++mi)
#pragma unroll
        for (int ni = 0; ni < 4; ++ni)
#pragma unroll
            for (int r = 0; r < 4; ++r) {
                int row = m0 + wr + mi * 16 + l4 * 4 + r;
                int col = n0 + wc + ni * 16 + l15;
                float v = acc[mi][ni][r] + bias[col];
                if (OUT_F32)
                    ((float*)Cout)[(size_t)row * N + col] = v;
                else
                    ((ushort_t*)Cout)[(size_t)row * N + col] = f2bf(v);
            }
}

// ---------------- flash attention ----------------
// qkv: [B*S][3072] bf16 (Q at +0, K at +1024, V at +2048, per head h*64)
// out: [B*S][1024] bf16
// Block = 4 independent waves; wave handles 16 q-rows. Swapped QK^T:
// s = mfma(Kfrag, Qfrag) -> S^T[key][q]: key=(l>>4)*4+r (+16*kt), q=l&15.
__global__ __launch_bounds__(256) void attn_kernel(const ushort_t* __restrict__ qkv,
                                                   ushort_t* __restrict__ out) {
    __shared__ __attribute__((aligned(16))) ushort_t P_lds[4][16][40];
    const int wave = threadIdx.x >> 6, lane = threadIdx.x & 63;
    const int l15 = lane & 15, l4 = lane >> 4;
    const int bq = blockIdx.x;            // 0..31 (q-block of 64)
    const int bh = blockIdx.y;            // 0..63
    const int b = bh >> 4, h = bh & 15;
    const int qbase = bq * 64 + wave * 16;
    const size_t RS = 3072;

    // Q fragments (also valid as MFMA B-operand for swapped QK^T)
    bf16x8 aq0, aq1;
    {
        const ushort_t* qp = qkv + (size_t)(b * SEQ + qbase + l15) * RS + h * 64 + l4 * 8;
        aq0 = *(const bf16x8*)(qp);
        aq1 = *(const bf16x8*)(qp + 32);
    }

    f32x4 o0 = {0.f,0.f,0.f,0.f}, o1 = {0.f,0.f,0.f,0.f},
          o2 = {0.f,0.f,0.f,0.f}, o3 = {0.f,0.f,0.f,0.f};
    float m_run = -INFINITY, l_run = 0.f;

    const int ntiles = (qbase + 15) / 32 + 1;    // causal: kbase <= qbase+15
    for (int t = 0; t < ntiles; ++t) {
        const int kbase = t * 32;
        // ---- QK^T (swapped) ----
        f32x4 s[2];
#pragma unroll
        for (int kt = 0; kt < 2; ++kt) {
            const ushort_t* kp = qkv + (size_t)(b * SEQ + kbase + kt * 16 + l15) * RS
                                 + 1024 + h * 64 + l4 * 8;
            bf16x8 ak0 = *(const bf16x8*)(kp);
            bf16x8 ak1 = *(const bf16x8*)(kp + 32);
            f32x4 z = {0.f,0.f,0.f,0.f};
            z = __builtin_amdgcn_mfma_f32_16x16x32_bf16(ak0, aq0, z, 0, 0, 0);
            z = __builtin_amdgcn_mfma_f32_16x16x32_bf16(ak1, aq1, z, 0, 0, 0);
            s[kt] = z;
        }
        // ---- mask + online softmax stats ----
        const int q = qbase + l15;
        float p[8];
        float pmax = -INFINITY;
#pragma unroll
        for (int kt = 0; kt < 2; ++kt)
#pragma unroll
            for (int r = 0; r < 4; ++r) {
                int key = kbase + kt * 16 + l4 * 4 + r;
                float v = s[kt][r] * SCALE;
                v = (key > q) ? -INFINITY : v;
                p[kt * 4 + r] = v;
                pmax = fmaxf(pmax, v);
            }
        pmax = fmaxf(pmax, __shfl_xor(pmax, 16));
        pmax = fmaxf(pmax, __shfl_xor(pmax, 32));
        const float m_new = fmaxf(m_run, pmax);
        const float scl = __expf(m_run - m_new);   // 0 on first tile
        float rsum = 0.f;
#pragma unroll
        for (int i = 0; i < 8; ++i) { p[i] = __expf(p[i] - m_new); rsum += p[i]; }
        rsum += __shfl_xor(rsum, 16);
        rsum += __shfl_xor(rsum, 32);
        l_run = l_run * scl + rsum;
        m_run = m_new;

        // ---- P -> LDS as [q=l15][key] bf16 ----
#pragma unroll
        for (int kt = 0; kt < 2; ++kt) {
            ushort4 pk;
            pk.x = f2bf(p[kt * 4 + 0]);
            pk.y = f2bf(p[kt * 4 + 1]);
            pk.z = f2bf(p[kt * 4 + 2]);
            pk.w = f2bf(p[kt * 4 + 3]);
            *(ushort4*)&P_lds[wave][l15][kt * 16 + l4 * 4] = pk;
        }

        // ---- rescale O (O rows are q = l4*4+r) ----
        float sc0 = __shfl(scl, l4 * 4 + 0);
        float sc1 = __shfl(scl, l4 * 4 + 1);
        float sc2 = __shfl(scl, l4 * 4 + 2);
        float sc3 = __shfl(scl, l4 * 4 + 3);
        o0[0] *= sc0; o0[1] *= sc1; o0[2] *= sc2; o0[3] *= sc3;
        o1[0] *= sc0; o1[1] *= sc1; o1[2] *= sc2; o1[3] *= sc3;
        o2[0] *= sc0; o2[1] *= sc1; o2[2] *= sc2; o2[3] *= sc3;
        o3[0] *= sc0; o3[1] *= sc1; o3[2] *= sc2; o3[3] *= sc3;

        // ---- PV ----
        bf16x8 pa = *(const bf16x8*)&P_lds[wave][l15][l4 * 8];
#pragma unroll
        for (int dt = 0; dt < 4; ++dt) {
            bf16x8 bv;
#pragma unroll
            for (int i = 0; i < 8; ++i) {
                int key = kbase + l4 * 8 + i;
                bv[i] = (short)qkv[(size_t)(b * SEQ + key) * RS + 2048 + h * 64 + dt * 16 + l15];
            }
            if (dt == 0) o0 = __builtin_amdgcn_mfma_f32_16x16x32_bf16(pa, bv, o0, 0, 0, 0);
            else if (dt == 1) o1 = __builtin_amdgcn_mfma_f32_16x16x32_bf16(pa, bv, o1, 0, 0, 0);
            else if (dt == 2) o2 = __builtin_amdgcn_mfma_f32_16x16x32_bf16(pa, bv, o2, 0, 0, 0);
            else o3 = __builtin_amdgcn_mfma_f32_16x16x32_bf16(pa, bv, o3, 0, 0, 0);
        }
    }

    // ---- epilogue: normalize and store ----
    float li0 = __shfl(l_run, l4 * 4 + 0);
    float li1 = __shfl(l_run, l4 * 4 + 1);
    float li2 = __shfl(l_run, l4 * 4 + 2);
    float li3 = __shfl(l_run, l4 * 4 + 3);
#pragma unroll
    for (int r = 0; r < 4; ++r) {
        int qr = qbase + l4 * 4 + r;
        ushort_t* op = out + (size_t)(b * SEQ + qr) * DM + h * 64 + l15;
        float li = (r == 0) ? li0 : (r == 1) ? li1 : (r == 2) ? li2 : li3;
        op[0]  = f2bf(((r==0)?o0[0]:(r==1)?o0[1]:(r==2)?o0[2]:o0[3]) / li);
        op[16] = f2bf(((r==0)?o1[0]:(r==1)?o1[1]:(r==2)?o1[2]:o1[3]) / li);
        op[32] = f2bf(((r==0)?o2[0]:(r==1)?o2[1]:(r==2)?o2[2]:o2[3]) / li);
        op[48] = f2bf(((r==0)?o3[0]:(r==1)?o3[1]:(r==2)?o3[2]:o3[3]) / li);
    }
}

// ---------------- launcher ----------------
extern "C" void kernel_launch(void* const* d_in, const int* in_sizes, int n_in,
                              void* d_out, int out_size, void* d_ws, size_t ws_size,
                              hipStream_t stream) {
    const float* x     = (const float*)d_in[0];
    // d_in[1] = mask (causal, implemented analytically)
    const float* W_qkv = (const float*)d_in[2];
    const float* b_qkv = (const float*)d_in[3];
    const float* W_out = (const float*)d_in[4];
    const float* b_out = (const float*)d_in[5];
    float* out = (float*)d_out;

    char* ws = (char*)d_ws;
    ushort_t* xb    = (ushort_t*)(ws);                      // 16,777,216 B
    ushort_t* WqkvT = (ushort_t*)(ws + 16777216);           //  6,291,456 B
    ushort_t* WoutT = (ushort_t*)(ws + 23068672);           //  2,097,152 B
    ushort_t* qkv   = (ushort_t*)(ws + 25165824);           // 50,331,648 B
    ushort_t* attn  = (ushort_t*)(ws + 75497472);           // 16,777,216 B  (total ~92 MB)

    const int nx = BATCH * SEQ * DM;                        // 8,388,608
    cast_f32_bf16<<<nx / (256 * 4), 256, 0, stream>>>(x, xb, nx);
    transpose_cast<<<dim3(3 * DM / 32, DM / 32), dim3(32, 8), 0, stream>>>(W_qkv, WqkvT, DM, 3 * DM);
    transpose_cast<<<dim3(DM / 32, DM / 32), dim3(32, 8), 0, stream>>>(W_out, WoutT, DM, DM);

    // QKV projection: [8192,1024] @ [1024,3072] -> bf16 qkv
    gemm_abt<false><<<dim3(3 * DM / 128, BATCH * SEQ / 128), 256, 0, stream>>>(
        xb, WqkvT, b_qkv, qkv, BATCH * SEQ, 3 * DM, DM);

    // attention
    attn_kernel<<<dim3(SEQ / 64, BATCH * NH), 256, 0, stream>>>(qkv, attn);

    // output projection: [8192,1024] @ [1024,1024] -> f32 out
    gemm_abt<true><<<dim3(DM / 128, BATCH * SEQ / 128), 256, 0, stream>>>(
        attn, WoutT, b_out, out, BATCH * SEQ, DM, DM);
}

// Round 2
// 379.583 us; speedup vs baseline: 1.5238x; 1.5238x over previous
//
#include <hip/hip_runtime.h>

// ---------------- problem constants ----------------
#define BATCH 4
#define SEQ 2048
#define DM 1024
#define NH 16
#define HD 64
#define SCALE 0.125f   // 64^-0.5

typedef unsigned short ushort_t;
typedef short bf16x8 __attribute__((ext_vector_type(8)));
typedef float f32x4 __attribute__((ext_vector_type(4)));

__device__ __forceinline__ ushort_t f2bf(float f) {
    unsigned u = __float_as_uint(f);
    unsigned r = (u + 0x7FFFu + ((u >> 16) & 1u)) >> 16;
    return (ushort_t)r;
}

__device__ __forceinline__ void glds16(const ushort_t* g, ushort_t* l) {
    __builtin_amdgcn_global_load_lds(
        (const __attribute__((address_space(1))) unsigned*)g,
        (__attribute__((address_space(3))) unsigned*)l, 16, 0, 0);
}

// ---------------- cast x: f32 -> bf16, 4 elems/thread ----------------
__global__ void cast_f32_bf16(const float* __restrict__ in, ushort_t* __restrict__ out, int n) {
    int i = (blockIdx.x * blockDim.x + threadIdx.x) * 4;
    if (i < n) {
        float4 v = *(const float4*)(in + i);
        ushort4 o;
        o.x = f2bf(v.x); o.y = f2bf(v.y); o.z = f2bf(v.z); o.w = f2bf(v.w);
        *(ushort4*)(out + i) = o;
    }
}

// ---------------- transpose+cast: in[K][N] f32 -> out[N][K] bf16 ----------------
__global__ void transpose_cast(const float* __restrict__ in, ushort_t* __restrict__ out,
                               int K, int N) {
    __shared__ float tile[32][33];
    int n0 = blockIdx.x * 32, k0 = blockIdx.y * 32;
    int x = threadIdx.x, y = threadIdx.y;   // blockDim = (32, 8)
#pragma unroll
    for (int j = 0; j < 32; j += 8)
        tile[y + j][x] = in[(size_t)(k0 + y + j) * N + n0 + x];
    __syncthreads();
#pragma unroll
    for (int j = 0; j < 32; j += 8)
        out[(size_t)(n0 + y + j) * K + k0 + x] = f2bf(tile[x][y + j]);
}

// ---------------- GEMM: C[M][N] = A[M][K] @ Bt[N][K]^T + bias[N] ----------------
// 128x128 tile, 256 threads (4 waves 2x2), BK=32, mfma_f32_16x16x32_bf16.
// Staging via global_load_lds width=16 into linear [128][32] LDS (pitch 64 B:
// b128 frag reads are bank-optimal: granule = 4*(row&1)+l4, 8 lanes each).
template <bool OUT_F32>
__global__ __launch_bounds__(256) void gemm_abt(
    const ushort_t* __restrict__ A, const ushort_t* __restrict__ Bt,
    const float* __restrict__ bias, void* __restrict__ Cout,
    int M, int N, int K) {
    __shared__ __attribute__((aligned(16))) ushort_t As[128 * 32];
    __shared__ __attribute__((aligned(16))) ushort_t Bs[128 * 32];
    const int tid = threadIdx.x;
    const int lane = tid & 63, wave = tid >> 6;
    const int l15 = lane & 15, l4 = lane >> 4;
    const int m0 = blockIdx.y * 128, n0 = blockIdx.x * 128;
    const int wr = (wave >> 1) * 64, wc = (wave & 1) * 64;

    // staging: wave w covers rows w*32..w*32+31 (2 calls of 16 rows each)
    const int srow = wave * 32 + (lane >> 2);
    const int scol = (lane & 3) * 8;
    const ushort_t* gA0 = A  + (size_t)(m0 + srow) * K + scol;
    const ushort_t* gB0 = Bt + (size_t)(n0 + srow) * K + scol;
    ushort_t* dA0 = &As[wave * 1024];
    ushort_t* dA1 = &As[wave * 1024 + 512];
    ushort_t* dB0 = &Bs[wave * 1024];
    ushort_t* dB1 = &Bs[wave * 1024 + 512];

    f32x4 acc[4][4];
#pragma unroll
    for (int i = 0; i < 4; ++i)
#pragma unroll
        for (int j = 0; j < 4; ++j) acc[i][j] = (f32x4){0.f, 0.f, 0.f, 0.f};

    for (int k0 = 0; k0 < K; k0 += 32) {
        glds16(gA0 + k0, dA0);
        glds16(gA0 + k0 + (size_t)16 * K, dA1);
        glds16(gB0 + k0, dB0);
        glds16(gB0 + k0 + (size_t)16 * K, dB1);
        __syncthreads();
        bf16x8 a[4], b[4];
#pragma unroll
        for (int i = 0; i < 4; ++i) {
            a[i] = *(const bf16x8*)&As[(wr + i * 16 + l15) * 32 + l4 * 8];
            b[i] = *(const bf16x8*)&Bs[(wc + i * 16 + l15) * 32 + l4 * 8];
        }
#pragma unroll
        for (int mi = 0; mi < 4; ++mi)
#pragma unroll
            for (int ni = 0; ni < 4; ++ni)
                acc[mi][ni] = __builtin_amdgcn_mfma_f32_16x16x32_bf16(
                    a[mi], b[ni], acc[mi][ni], 0, 0, 0);
        __syncthreads();
    }

#pragma unroll
    for (int mi = 0; mi < 4; ++mi)
#pragma unroll
        for (int ni = 0; ni < 4; ++ni)
#pragma unroll
            for (int r = 0; r < 4; ++r) {
                int row = m0 + wr + mi * 16 + l4 * 4 + r;
                int col = n0 + wc + ni * 16 + l15;
                float v = acc[mi][ni][r] + bias[col];
                if (OUT_F32)
                    ((float*)Cout)[(size_t)row * N + col] = v;
                else
                    ((ushort_t*)Cout)[(size_t)row * N + col] = f2bf(v);
            }
}

// ---------------- flash attention ----------------
// qkv: [B*S][3072] bf16 (Q +0, K +1024, V +2048; head at h*64)
// Block = 64 q-rows (4 waves x 16), KV tile = 64 keys staged in LDS.
// K staged via global_load_lds with pre-swizzled source; V staged transposed
// (Vt[d][key]) via reg->scalar LDS writes. XOR swizzle: 16B-chunk ^= (row&7).
__global__ __launch_bounds__(256) void attn_kernel(const ushort_t* __restrict__ qkv,
                                                   ushort_t* __restrict__ out) {
    __shared__ __attribute__((aligned(16))) ushort_t Ks[64 * 64];
    __shared__ __attribute__((aligned(16))) ushort_t Vt[64 * 64];
    __shared__ __attribute__((aligned(16))) ushort_t Pl[4][16 * 64];
    const int tid = threadIdx.x;
    const int wave = tid >> 6, lane = tid & 63;
    const int l15 = lane & 15, l4 = lane >> 4;
    const int bq = ((int)gridDim.x - 1) - (int)blockIdx.x;   // heavy blocks first
    const int bh = blockIdx.y;
    const int b = bh >> 4, h = bh & 15;
    const int qbase = bq * 64 + wave * 16;
    const size_t RS = 3072;
    const size_t rowbase = (size_t)b * SEQ;

    // Q fragments (serve as MFMA B-operand for swapped QK^T)
    bf16x8 aq0, aq1;
    {
        const ushort_t* qp = qkv + (rowbase + qbase + l15) * RS + h * 64 + l4 * 8;
        aq0 = *(const bf16x8*)(qp);
        aq1 = *(const bf16x8*)(qp + 32);
    }

    f32x4 o[4];
#pragma unroll
    for (int i = 0; i < 4; ++i) o[i] = (f32x4){0.f, 0.f, 0.f, 0.f};
    float m_run = -INFINITY, l_run = 0.f;

    // K staging source (pre-swizzled): wave w stages rows w*16+c*8+(lane>>3),
    // source chunk = (lane&7) ^ ((lane>>3)&7)  [row&7 == (lane>>3)&7]
    const int krow = lane >> 3;                    // 0..7
    const int kch = (lane & 7) ^ krow;             // swizzled source 16B chunk
    // V staging: thread -> key=tid&63, d0=(tid>>6)*16
    const int sv_key = tid & 63;
    const int sv_d0 = (tid >> 6) * 16;

    for (int t = 0; t <= bq; ++t) {
        const int kbase = t * 64;
        // ---- stage K via global_load_lds (2 calls/wave, 16 rows each) ----
#pragma unroll
        for (int c = 0; c < 2; ++c) {
            const ushort_t* gk = qkv + (rowbase + kbase + wave * 16 + c * 8 + krow) * RS
                                 + 1024 + h * 64 + kch * 8;
            glds16(gk, &Ks[(wave * 16 + c * 8) * 64]);
        }
        // ---- stage V transposed: Vt[d][key ^ ((d&7)<<3)] ----
        {
            const ushort_t* gv = qkv + (rowbase + kbase + sv_key) * RS + 2048 + h * 64 + sv_d0;
            bf16x8 v0 = *(const bf16x8*)gv;
            bf16x8 v1 = *(const bf16x8*)(gv + 8);
#pragma unroll
            for (int j = 0; j < 8; ++j) {
                int d = sv_d0 + j;
                Vt[d * 64 + (sv_key ^ ((d & 7) << 3))] = (ushort_t)v0[j];
                int d2 = sv_d0 + 8 + j;
                Vt[d2 * 64 + (sv_key ^ ((d2 & 7) << 3))] = (ushort_t)v1[j];
            }
        }
        __syncthreads();

        // ---- QK^T (swapped): s = K_tile . Q^T -> S^T[key][q] ----
        f32x4 s[4];
#pragma unroll
        for (int kt = 0; kt < 4; ++kt) {
            int row = kt * 16 + l15;
            int r7 = row & 7;
            bf16x8 ak0 = *(const bf16x8*)&Ks[row * 64 + ((l4 ^ r7) * 8)];
            bf16x8 ak1 = *(const bf16x8*)&Ks[row * 64 + (((4 + l4) ^ r7) * 8)];
            f32x4 z = {0.f, 0.f, 0.f, 0.f};
            z = __builtin_amdgcn_mfma_f32_16x16x32_bf16(ak0, aq0, z, 0, 0, 0);
            z = __builtin_amdgcn_mfma_f32_16x16x32_bf16(ak1, aq1, z, 0, 0, 0);
            s[kt] = z;
        }

        // ---- scale + mask + online softmax ----
        const int q = qbase + l15;
        float p[16];
        float pmax = -INFINITY;
#pragma unroll
        for (int kt = 0; kt < 4; ++kt)
#pragma unroll
            for (int r = 0; r < 4; ++r)
                p[kt * 4 + r] = s[kt][r] * SCALE;
        if (t == bq) {   // only the diagonal tile needs masking (uniform branch)
#pragma unroll
            for (int kt = 0; kt < 4; ++kt)
#pragma unroll
                for (int r = 0; r < 4; ++r) {
                    int key = kbase + kt * 16 + l4 * 4 + r;
                    if (key > q) p[kt * 4 + r] = -INFINITY;
                }
        }
#pragma unroll
        for (int i = 0; i < 16; ++i) pmax = fmaxf(pmax, p[i]);
        pmax = fmaxf(pmax, __shfl_xor(pmax, 16));
        pmax = fmaxf(pmax, __shfl_xor(pmax, 32));
        const float m_new = fmaxf(m_run, pmax);
        const float scl = __expf(m_run - m_new);   // 0 on first tile
        float rsum = 0.f;
#pragma unroll
        for (int i = 0; i < 16; ++i) { p[i] = __expf(p[i] - m_new); rsum += p[i]; }
        rsum += __shfl_xor(rsum, 16);
        rsum += __shfl_xor(rsum, 32);
        l_run = l_run * scl + rsum;
        m_run = m_new;

        // ---- P -> LDS (swizzled), row q=l15, keys kt*16+l4*4.. ----
#pragma unroll
        for (int kt = 0; kt < 4; ++kt) {
            ushort4 pk;
            pk.x = f2bf(p[kt * 4 + 0]);
            pk.y = f2bf(p[kt * 4 + 1]);
            pk.z = f2bf(p[kt * 4 + 2]);
            pk.w = f2bf(p[kt * 4 + 3]);
            int off = (kt * 16 + l4 * 4) ^ ((l15 & 7) << 3);
            *(ushort4*)&Pl[wave][l15 * 64 + off] = pk;
        }

        // ---- rescale O (rows q = l4*4+r) ----
        float sc0 = __shfl(scl, l4 * 4 + 0);
        float sc1 = __shfl(scl, l4 * 4 + 1);
        float sc2 = __shfl(scl, l4 * 4 + 2);
        float sc3 = __shfl(scl, l4 * 4 + 3);
#pragma unroll
        for (int dt = 0; dt < 4; ++dt) {
            o[dt][0] *= sc0; o[dt][1] *= sc1; o[dt][2] *= sc2; o[dt][3] *= sc3;
        }

        // ---- PV: o[q][d] += P[q][key] V[key][d] ----
        const int pr7 = l15 & 7;
        bf16x8 pa0 = *(const bf16x8*)&Pl[wave][l15 * 64 + ((l4 ^ pr7) * 8)];
        bf16x8 pa1 = *(const bf16x8*)&Pl[wave][l15 * 64 + (((4 + l4) ^ pr7) * 8)];
#pragma unroll
        for (int dt = 0; dt < 4; ++dt) {
            int d = dt * 16 + l15;
            int r7 = d & 7;
            bf16x8 bv0 = *(const bf16x8*)&Vt[d * 64 + ((l4 ^ r7) * 8)];
            bf16x8 bv1 = *(const bf16x8*)&Vt[d * 64 + (((4 + l4) ^ r7) * 8)];
            o[dt] = __builtin_amdgcn_mfma_f32_16x16x32_bf16(pa0, bv0, o[dt], 0, 0, 0);
            o[dt] = __builtin_amdgcn_mfma_f32_16x16x32_bf16(pa1, bv1, o[dt], 0, 0, 0);
        }
        __syncthreads();
    }

    // ---- epilogue: normalize and store ----
    float li0 = __shfl(l_run, l4 * 4 + 0);
    float li1 = __shfl(l_run, l4 * 4 + 1);
    float li2 = __shfl(l_run, l4 * 4 + 2);
    float li3 = __shfl(l_run, l4 * 4 + 3);
#pragma unroll
    for (int r = 0; r < 4; ++r) {
        int qr = qbase + l4 * 4 + r;
        float li = (r == 0) ? li0 : (r == 1) ? li1 : (r == 2) ? li2 : li3;
        ushort_t* op = out + (rowbase + qr) * DM + h * 64 + l15;
#pragma unroll
        for (int dt = 0; dt < 4; ++dt)
            op[dt * 16] = f2bf(o[dt][r] / li);
    }
}

// ---------------- launcher ----------------
extern "C" void kernel_launch(void* const* d_in, const int* in_sizes, int n_in,
                              void* d_out, int out_size, void* d_ws, size_t ws_size,
                              hipStream_t stream) {
    const float* x     = (const float*)d_in[0];
    // d_in[1] = mask (causal, implemented analytically)
    const float* W_qkv = (const float*)d_in[2];
    const float* b_qkv = (const float*)d_in[3];
    const float* W_out = (const float*)d_in[4];
    const float* b_out = (const float*)d_in[5];
    float* out = (float*)d_out;

    char* ws = (char*)d_ws;
    ushort_t* xb    = (ushort_t*)(ws);                      // 16,777,216 B
    ushort_t* WqkvT = (ushort_t*)(ws + 16777216);           //  6,291,456 B
    ushort_t* WoutT = (ushort_t*)(ws + 23068672);           //  2,097,152 B
    ushort_t* qkv   = (ushort_t*)(ws + 25165824);           // 50,331,648 B
    ushort_t* attn  = (ushort_t*)(ws + 75497472);           // 16,777,216 B

    const int nx = BATCH * SEQ * DM;                        // 8,388,608
    cast_f32_bf16<<<nx / (256 * 4), 256, 0, stream>>>(x, xb, nx);
    transpose_cast<<<dim3(3 * DM / 32, DM / 32), dim3(32, 8), 0, stream>>>(W_qkv, WqkvT, DM, 3 * DM);
    transpose_cast<<<dim3(DM / 32, DM / 32), dim3(32, 8), 0, stream>>>(W_out, WoutT, DM, DM);

    // QKV projection: [8192,1024] @ [1024,3072] -> bf16 qkv
    gemm_abt<false><<<dim3(3 * DM / 128, BATCH * SEQ / 128), 256, 0, stream>>>(
        xb, WqkvT, b_qkv, qkv, BATCH * SEQ, 3 * DM, DM);

    // attention
    attn_kernel<<<dim3(SEQ / 64, BATCH * NH), 256, 0, stream>>>(qkv, attn);

    // output projection: [8192,1024] @ [1024,1024] -> f32 out
    gemm_abt<true><<<dim3(DM / 128, BATCH * SEQ / 128), 256, 0, stream>>>(
        attn, WoutT, b_out, out, BATCH * SEQ, DM, DM);
}